// Round 1
// baseline (702.233 us; speedup 1.0000x reference)
//
#include <hip/hip_runtime.h>
#include <stdint.h>

#define N_BOX 8400
#define NCLS 80
#define PSTRIDE 85
#define NW 132            // 64-bit words covering 8400
#define CONF_T 0.01f
#define NMS_T 0.2f

typedef unsigned long long u64;

// ws layout (bytes)
#define OFF_DET     0                    // 8400 x 8 f32   = 268800
#define OFF_BOXES   268800               // 8400 float4    = 134400
#define OFF_KEYS    403200               // 8400 u64       = 67200
#define OFF_SIDX    470400               // 8400 int       = 33600
#define OFF_DETS    504000               // 8400 x 8 f32   = 268800
#define OFF_BOXESS  772800               // 8400 float4    = 134400
#define OFF_MASK    907200               // 8400 x 132 u64 = 8870400
#define OFF_KEEPW   9777600              // 132 u64        = 1056
#define OFF_VCNT    9778656              // 1 int

__device__ __forceinline__ unsigned fmap_desc(float f) {
    unsigned u = __float_as_uint(f);
    unsigned m = (u & 0x80000000u) ? ~u : (u | 0x80000000u); // monotone ascending
    return ~m;                                               // descending
}

// ---- kernel A: per-row preprocess ----
__global__ __launch_bounds__(256) void prep_k(const float* __restrict__ pred,
                                              float* __restrict__ det,
                                              float4* __restrict__ boxes,
                                              u64* __restrict__ keys,
                                              int* __restrict__ vcount) {
    int i = blockIdx.x * 256 + threadIdx.x;
    if (i >= N_BOX) return;
    const float* p = pred + (size_t)i * PSTRIDE;
    float cx = p[0], cy = p[1], w = p[2], h = p[3], obj = p[4];
    float hw = __fmul_rn(w, 0.5f), hh = __fmul_rn(h, 0.5f);
    float x1 = __fsub_rn(cx, hw), y1 = __fsub_rn(cy, hh);
    float x2 = __fadd_rn(cx, hw), y2 = __fadd_rn(cy, hh);
    float best = p[5];
    int arg = 0;
    for (int c = 1; c < NCLS; ++c) {
        float v = p[5 + c];
        if (v > best) { best = v; arg = c; }   // strict > keeps FIRST max (numpy argmax)
    }
    bool valid = (obj >= CONF_T);
    float score = valid ? obj : -1.0f;
    if (valid) atomicAdd(vcount, 1);
    keys[i] = ((u64)fmap_desc(score) << 32) | (unsigned)i;  // sort asc => score desc, idx asc (stable)
    float* d = det + (size_t)i * 8;
    d[0] = x1; d[1] = y1; d[2] = x2; d[3] = y2;
    d[4] = obj; d[5] = best; d[6] = (float)arg; d[7] = 0.0f;
    boxes[i] = make_float4(x1, y1, x2, y2);
}

// ---- kernel B: rank = #{keys < mine}; scatter index ----
__global__ __launch_bounds__(256) void rank_k(const u64* __restrict__ keys,
                                              int* __restrict__ sidx) {
    __shared__ u64 kl[4200];
    int i = blockIdx.x * 256 + threadIdx.x;
    bool act = (i < N_BOX);
    u64 my = act ? keys[i] : 0ull;
    int cnt = 0;
    for (int half = 0; half < 2; ++half) {
        int base = half * 4200;
        __syncthreads();
        for (int j = threadIdx.x; j < 4200; j += 256) kl[j] = keys[base + j];
        __syncthreads();
        if (act) {
            for (int j = 0; j < 4200; ++j) cnt += (kl[j] < my) ? 1 : 0;
        }
    }
    if (act) sidx[cnt] = i;   // all keys distinct (index embedded) -> permutation
}

// ---- kernel C: gather sorted det/boxes ----
__global__ __launch_bounds__(256) void gather_k(const int* __restrict__ sidx,
                                                const float4* __restrict__ det,
                                                const float4* __restrict__ boxes,
                                                float4* __restrict__ det_s,
                                                float4* __restrict__ boxes_s) {
    int r = blockIdx.x * 256 + threadIdx.x;
    if (r >= N_BOX) return;
    int i = sidx[r];
    det_s[r * 2]     = det[i * 2];
    det_s[r * 2 + 1] = det[i * 2 + 1];
    boxes_s[r]       = boxes[i];
}

// ---- kernel D: suppression bitmask (upper triangle), torchvision-style ----
__global__ __launch_bounds__(64) void mask_k(const float4* __restrict__ boxes_s,
                                             u64* __restrict__ mask) {
    int cb = blockIdx.x, rb = blockIdx.y, t = threadIdx.x;
    int r = rb * 64 + t;
    if (cb < rb) {                       // lower triangle: zero-fill (ws is poisoned)
        if (r < N_BOX) mask[(size_t)r * NW + cb] = 0ull;
        return;
    }
    __shared__ float4 cB[64];
    __shared__ float  cA[64];
    int c0 = cb * 64 + t;
    float4 b = (c0 < N_BOX) ? boxes_s[c0] : make_float4(0.f, 0.f, 0.f, 0.f);
    cB[t] = b;
    cA[t] = __fmul_rn(__fsub_rn(b.z, b.x), __fsub_rn(b.w, b.y));
    __syncthreads();
    if (r >= N_BOX) return;
    float4 rx = boxes_s[r];
    float ra = __fmul_rn(__fsub_rn(rx.z, rx.x), __fsub_rn(rx.w, rx.y));
    u64 bits = 0ull;
    int cbase = cb * 64;
    for (int j = 0; j < 64; ++j) {
        int c = cbase + j;
        if (c >= N_BOX || c <= r) continue;
        float4 cx4 = cB[j];
        float ltx = fmaxf(rx.x, cx4.x), lty = fmaxf(rx.y, cx4.y);
        float rbx = fminf(rx.z, cx4.z), rby = fminf(rx.w, cx4.w);
        float wx = fmaxf(__fsub_rn(rbx, ltx), 0.0f);
        float wy = fmaxf(__fsub_rn(rby, lty), 0.0f);
        float inter = __fmul_rn(wx, wy);
        // numpy order: ((area_i + area_j) - inter) + 1e-9
        float denom = __fadd_rn(__fsub_rn(__fadd_rn(ra, cA[j]), inter), 1e-9f);
        float iou = __fdiv_rn(inter, denom);
        if (iou > NMS_T) bits |= (1ull << j);
    }
    mask[(size_t)r * NW + cb] = bits;
}

// ---- kernel E: serial greedy scan, one wave ----
__global__ __launch_bounds__(64) void scan_k(const u64* __restrict__ mask,
                                             const int* __restrict__ vcount,
                                             u64* __restrict__ keepw) {
    __shared__ u64 remv[NW];
    int lane = threadIdx.x;
    for (int w0 = lane; w0 < NW; w0 += 64) remv[w0] = 0ull;
    __syncthreads();
    int V = *vcount;
    for (int w = 0; w < NW; ++w) {
        int base = w << 6;
        if (base >= V) break;
        __syncthreads();
        u64 cur = remv[w];                 // wave-uniform (same address broadcast)
        int nb = min(64, V - base);
        for (int b = 0; b < nb; ++b) {
            if ((cur >> b) & 1ull) continue;     // uniform branch
            const u64* row = mask + (size_t)(base + b) * NW;
            for (int wd = w + lane; wd < NW; wd += 64)
                remv[wd] |= row[wd];             // distinct wd per lane
            cur |= row[w];                       // broadcast load keeps cur in sync
        }
    }
    __syncthreads();
    for (int w0 = lane; w0 < NW; w0 += 64) {
        int base = w0 << 6;
        u64 vm;
        if (base + 64 <= V)      vm = ~0ull;
        else if (base >= V)      vm = 0ull;
        else                     vm = (1ull << (V - base)) - 1ull;
        keepw[w0] = (~remv[w0]) & vm;
    }
}

// ---- kernel F: masked write-out (7 cols) ----
__global__ __launch_bounds__(256) void out_k(const float* __restrict__ det_s,
                                             const u64* __restrict__ keepw,
                                             float* __restrict__ out) {
    int e = blockIdx.x * 256 + threadIdx.x;
    if (e >= N_BOX * 7) return;
    int r = e / 7, c = e - r * 7;
    bool k = (keepw[r >> 6] >> (r & 63)) & 1ull;
    out[e] = k ? det_s[r * 8 + c] : 0.0f;
}

extern "C" void kernel_launch(void* const* d_in, const int* in_sizes, int n_in,
                              void* d_out, int out_size, void* d_ws, size_t ws_size,
                              hipStream_t stream) {
    const float* pred = (const float*)d_in[0];
    char* ws = (char*)d_ws;
    float*  det     = (float*) (ws + OFF_DET);
    float4* boxes   = (float4*)(ws + OFF_BOXES);
    u64*    keys    = (u64*)   (ws + OFF_KEYS);
    int*    sidx    = (int*)   (ws + OFF_SIDX);
    float*  det_s   = (float*) (ws + OFF_DETS);
    float4* boxes_s = (float4*)(ws + OFF_BOXESS);
    u64*    mask    = (u64*)   (ws + OFF_MASK);
    u64*    keepw   = (u64*)   (ws + OFF_KEEPW);
    int*    vcount  = (int*)   (ws + OFF_VCNT);

    hipMemsetAsync(vcount, 0, 4, stream);
    prep_k  <<<(N_BOX + 255) / 256, 256, 0, stream>>>(pred, det, boxes, keys, vcount);
    rank_k  <<<(N_BOX + 255) / 256, 256, 0, stream>>>(keys, sidx);
    gather_k<<<(N_BOX + 255) / 256, 256, 0, stream>>>(sidx, (const float4*)det, boxes,
                                                      (float4*)det_s, boxes_s);
    mask_k  <<<dim3(NW, NW), 64, 0, stream>>>(boxes_s, mask);
    scan_k  <<<1, 64, 0, stream>>>(mask, vcount, keepw);
    out_k   <<<(N_BOX * 7 + 255) / 256, 256, 0, stream>>>(det_s, keepw, (float*)d_out);
}